// Round 6
// baseline (1024.417 us; speedup 1.0000x reference)
//
#include <hip/hip_runtime.h>
#include <hip/hip_bf16.h>

#define FIELD 26
#define VOCAB 100000
#define ED 32
#define KZ 832      // 26*32
#define KP 676      // 26*26
#define NH 256
#define ND 13
#define H1 128
#define NBATCH 16384

__device__ __forceinline__ int clampidx(int idx) {
    return idx < 0 ? 0 : (idx >= VOCAB ? VOCAB - 1 : idx);
}

// ---------------------------------------------------------------------------
// Conservative fully-fused fp32 PNN forward. 8 samples/block, 61.9 KB LDS,
// 256 threads. No MFMA, no global_load_lds, no vector-type casts beyond
// float4, no workspace. Every index bounded by construction.
//
// Per block: gather 208 embedding rows -> z_s; p = per-sample 26x26 Gram
// matrix; l1[h] = sum_k z*wz + sum_j p*wp + lb (thread h owns unit h for all
// 8 samples; wz/wp reads coalesced across h and L2-resident after block 0);
// hidden = relu(l1 @ W1 + b1); out = sigmoid(h @ Wf + bf).
// ---------------------------------------------------------------------------
__global__ __launch_bounds__(256) void kf_all(const float* __restrict__ dense,
                                              const int* __restrict__ sparse,
                                              const float* __restrict__ tables,
                                              const float* __restrict__ wz,
                                              const float* __restrict__ wp,
                                              const float* __restrict__ lb,
                                              const float* __restrict__ W1,
                                              const float* __restrict__ b1,
                                              const float* __restrict__ Wf,
                                              const float* __restrict__ bfp,
                                              float* __restrict__ out) {
    __shared__ int idx_s[8 * FIELD];               // 832 B
    __shared__ __align__(16) float z_s[8][KZ];     // 26.6 KB
    __shared__ float p_s[8][KP];                   // 21.6 KB
    __shared__ float l1_s[8][272];                 // 8.7 KB  (269 used, 3 zero-pad)
    __shared__ float h_s[8][H1];                   // 4 KB
    int t = threadIdx.x;
    int b0 = blockIdx.x * 8;

    if (t < 8 * FIELD) idx_s[t] = clampidx(sparse[b0 * FIELD + t]);
    __syncthreads();

    // gather: 208 (sample,field) rows x 8 float4 each
    for (int i = t; i < 8 * FIELD * 8; i += 256) {
        int r = i >> 3, q = i & 7;
        int s = r / FIELD, f = r - s * FIELD;
        const float* src = tables + (long)(f * VOCAB + idx_s[r]) * ED + q * 4;
        *(float4*)&z_s[s][f * ED + q * 4] = *(const float4*)src;
    }
    __syncthreads();

    // p[s][f*26+g] = <z_s[s][f], z_s[s][g]>
    for (int j = t; j < 8 * KP; j += 256) {
        int s = j / KP, r = j - s * KP;
        int f = r / FIELD, g = r - f * FIELD;
        const float* zf = &z_s[s][f * ED];
        const float* zg = &z_s[s][g * ED];
        float acc = 0.f;
#pragma unroll
        for (int e = 0; e < ED; ++e) acc += zf[e] * zg[e];
        p_s[s][r] = acc;
    }
    __syncthreads();

    // l1: thread t owns output unit h = t for all 8 samples.
    {
        int h = t;
        float accs[8];
        float lbv = lb[h];
#pragma unroll
        for (int s = 0; s < 8; ++s) accs[s] = lbv;
        for (int k = 0; k < KZ; ++k) {
            float wv = wz[k * NH + h];              // coalesced across h
#pragma unroll
            for (int s = 0; s < 8; ++s) accs[s] += z_s[s][k] * wv;   // broadcast
        }
        for (int j = 0; j < KP; ++j) {
            float wv = wp[j * NH + h];
#pragma unroll
            for (int s = 0; s < 8; ++s) accs[s] += p_s[s][j] * wv;
        }
#pragma unroll
        for (int s = 0; s < 8; ++s) l1_s[s][h] = accs[s] > 0.f ? accs[s] : 0.f;
    }
    if (t < 8 * ND) {                               // dense part of concat, relu'd
        int s = t / ND, d = t - s * ND;
        float v = dense[(long)(b0 + s) * ND + d];
        l1_s[s][NH + d] = v > 0.f ? v : 0.f;
    }
    if (t < 8 * 3) {                                // zero the 3-slot pad
        int s = t / 3;
        l1_s[s][NH + ND + (t % 3)] = 0.f;
    }
    __syncthreads();

    // hidden layer: 8*128 outputs
    for (int idx = t; idx < 8 * H1; idx += 256) {
        int s = idx >> 7, j = idx & 127;
        float acc = b1[j];
        for (int i = 0; i < NH + ND; ++i) acc += l1_s[s][i] * W1[i * H1 + j];
        h_s[s][j] = acc > 0.f ? acc : 0.f;
    }
    __syncthreads();

    // final dot + sigmoid, one thread per sample
    if (t < 8) {
        float acc = bfp[0];
        const float* hp = h_s[t];
#pragma unroll
        for (int q = 0; q < H1; ++q) acc += hp[q] * Wf[q];
        out[b0 + t] = 1.f / (1.f + __expf(-acc));
    }
}

// ---------------------------------------------------------------------------
extern "C" void kernel_launch(void* const* d_in, const int* in_sizes, int n_in,
                              void* d_out, int out_size, void* d_ws, size_t ws_size,
                              hipStream_t stream) {
    const float* dense   = (const float*)d_in[0];
    const int*   sparse  = (const int*)d_in[1];
    const float* tables  = (const float*)d_in[2];
    const float* wz      = (const float*)d_in[3];
    const float* wp      = (const float*)d_in[4];
    const float* lb      = (const float*)d_in[5];
    const float* W1      = (const float*)d_in[6];
    const float* b1      = (const float*)d_in[7];
    const float* Wf      = (const float*)d_in[8];
    const float* bfp     = (const float*)d_in[9];
    float* out           = (float*)d_out;

    kf_all<<<NBATCH / 8, 256, 0, stream>>>(dense, sparse, tables, wz, wp, lb,
                                           W1, b1, Wf, bfp, out);
}